// Round 13
// baseline (279.403 us; speedup 1.0000x reference)
//
#include <hip/hip_runtime.h>
#include <stdint.h>

// Problem constants (B=4, N=2048, D=384, heads=6, hd=64)
#define NB 4
#define NN 2048
#define ND 384
#define NH 6
#define HD 64
#define ROWS (NB * NN)  // 8192

typedef int v4i __attribute__((ext_vector_type(4)));
typedef float v4f __attribute__((ext_vector_type(4)));
typedef float v2f __attribute__((ext_vector_type(2)));
typedef _Float16 half_t;
typedef half_t v8h __attribute__((ext_vector_type(8)));

// VOP3P packed fp32 FMA with op_sel scalar-broadcast (no dup movs).
#define PK_FMA_LO(accv, ap, bp)                                            \
    asm("v_pk_fma_f32 %0, %1, %2, %0 op_sel:[0,0,0] op_sel_hi:[0,1,1]"     \
        : "+v"(accv) : "v"(ap), "v"(bp))
#define PK_FMA_HI(accv, ap, bp)                                            \
    asm("v_pk_fma_f32 %0, %1, %2, %0 op_sel:[1,0,0] op_sel_hi:[1,1,1]"     \
        : "+v"(accv) : "v"(ap), "v"(bp))

// ---------------------------------------------------------------------------
// Kernel 1 v11 (R23): fused QKV projection — OCCUPANCY round.
// Six rounds of inner-loop variants all saturate at ~94-97us with
// VALUBusy ~60% and occupancy pinned at 23% (grid 768 = exactly 3
// blocks/CU). Surviving theory: per-K-tile barrier drains (vmcnt(0) at
// s_barrier) exposed; 3 independent blocks/CU can't hide them.
// Fix: 64-row blocks -> grid 128x12 = 1536 = 6 blocks/CU = 24 waves/CU.
// Thread tile 4x6 (12 pk/kk, 24 acc VGPRs). LDS 22KB/block (A pitch 72:
// staging writes <=2-way = free). Per-output ascending-k chain unchanged
// -> bit-identical Q/K/V.
// ---------------------------------------------------------------------------
__global__ __launch_bounds__(256, 6) void qkv_gemm_kernel(
    const float* __restrict__ X,
    const float* __restrict__ Wq, const float* __restrict__ Wk, const float* __restrict__ Wv,
    const float* __restrict__ Bq, const float* __restrict__ Bk, const float* __restrict__ Bv,
    int8_t* __restrict__ Q8, int8_t* __restrict__ K8, int8_t* __restrict__ V8T,
    int* __restrict__ CS)
{
    __shared__ __attribute__((aligned(16))) float As[2][16][72];   // [buf][k][row]
    __shared__ __attribute__((aligned(16))) float Bs[2][16][100];  // [buf][k][col]
    __shared__ int lcol[96];

    const int t = threadIdx.x;          // 0..255
    const int tx = t & 15;              // col group (6 cols: 4 + 2)
    const int ty = t >> 4;              // row group (4 rows, 0..15)
    const int row0 = blockIdx.x * 64;
    const int m = blockIdx.y >> 2;      // 0=Q 1=K 2=V
    const int cl0 = (blockIdx.y & 3) * 96;
    const float* W = (m == 0) ? Wq : (m == 1) ? Wk : Wv;
    const float* Bi = (m == 0) ? Bq : (m == 1) ? Bk : Bv;

    // staging maps: A rows by thread quads (1 float4 each); B cols by pairs
    const int sr4 = t >> 2;             // 0..63
    const int kc4 = (t & 3) * 4;        // k sub-chunk 0/4/8/12
    const int srB = t >> 1;             // 0..95 (t<192)
    const int skB = (t & 1) * 8;
    const float* xp = X + (size_t)(row0 + sr4) * ND + kc4;
    const float* wp = W + (size_t)(cl0 + srB) * ND + skB;

    v2f acc[4][3];
#pragma unroll
    for (int i = 0; i < 4; ++i)
#pragma unroll
        for (int p = 0; p < 3; ++p) acc[i][p] = (v2f)0.0f;

    float4 xa = *(const float4*)xp;
    float4 wb0, wb1;
    if (t < 192) { wb0 = *(const float4*)wp; wb1 = *(const float4*)(wp + 4); }

    int cur = 0;
    for (int k0 = 0; k0 < ND; k0 += 16) {
        As[cur][kc4 + 0][sr4] = xa.x; As[cur][kc4 + 1][sr4] = xa.y;
        As[cur][kc4 + 2][sr4] = xa.z; As[cur][kc4 + 3][sr4] = xa.w;
        if (t < 192) {
            Bs[cur][skB + 0][srB] = wb0.x; Bs[cur][skB + 1][srB] = wb0.y;
            Bs[cur][skB + 2][srB] = wb0.z; Bs[cur][skB + 3][srB] = wb0.w;
            Bs[cur][skB + 4][srB] = wb1.x; Bs[cur][skB + 5][srB] = wb1.y;
            Bs[cur][skB + 6][srB] = wb1.z; Bs[cur][skB + 7][srB] = wb1.w;
        }

        if (k0 + 16 < ND) {                 // prefetch next K-tile into regs
            xa = *(const float4*)(xp + k0 + 16);
            if (t < 192) {
                wb0 = *(const float4*)(wp + k0 + 16);
                wb1 = *(const float4*)(wp + k0 + 20);
            }
        }
        __syncthreads();                    // buf[cur] ready; buf[cur^1] free

#pragma unroll
        for (int kk = 0; kk < 16; ++kk) {
            v4f a0 = *(const v4f*)&As[cur][kk][ty * 4];       // b128 (4 rows)
            v4f b0 = *(const v4f*)&Bs[cur][kk][tx * 4];       // b128
            v2f bp2 = *(const v2f*)&Bs[cur][kk][64 + tx * 2]; // b64
            v2f ap0 = __builtin_shufflevector(a0, a0, 0, 1);
            v2f ap1 = __builtin_shufflevector(a0, a0, 2, 3);
            v2f bp0 = __builtin_shufflevector(b0, b0, 0, 1);
            v2f bp1 = __builtin_shufflevector(b0, b0, 2, 3);

            PK_FMA_LO(acc[0][0], ap0, bp0); PK_FMA_LO(acc[0][1], ap0, bp1);
            PK_FMA_LO(acc[0][2], ap0, bp2);
            PK_FMA_HI(acc[1][0], ap0, bp0); PK_FMA_HI(acc[1][1], ap0, bp1);
            PK_FMA_HI(acc[1][2], ap0, bp2);

            PK_FMA_LO(acc[2][0], ap1, bp0); PK_FMA_LO(acc[2][1], ap1, bp1);
            PK_FMA_LO(acc[2][2], ap1, bp2);
            PK_FMA_HI(acc[3][0], ap1, bp0); PK_FMA_HI(acc[3][1], ap1, bp1);
            PK_FMA_HI(acc[3][2], ap1, bp2);
        }
        cur ^= 1;
    }

    const int bidx = row0 >> 11;
    const int n0 = row0 & 2047;
    const int c1 = cl0 + tx * 4;
    const int c2 = cl0 + 64 + tx * 2;
    const int h1 = c1 >> 6, d1 = c1 & 63;
    const int h2 = c2 >> 6, d2 = c2 & 63;

    if (m != 2) {
        int8_t* Out = (m == 0) ? Q8 : K8;
        const float b1a = Bi[c1], b1b = Bi[c1 + 1], b1c = Bi[c1 + 2], b1d = Bi[c1 + 3];
        const float b2a = Bi[c2], b2b = Bi[c2 + 1];
#pragma unroll
        for (int i = 0; i < 4; ++i) {
            const int n = n0 + ty * 4 + i;
            float v0 = acc[i][0][0] + b1a, v1 = acc[i][0][1] + b1b;
            float v2 = acc[i][1][0] + b1c, v3 = acc[i][1][1] + b1d;
            int q0 = max(-128, min(127, (int)floorf(v0 * 64.0f)));
            int q1 = max(-128, min(127, (int)floorf(v1 * 64.0f)));
            int q2 = max(-128, min(127, (int)floorf(v2 * 64.0f)));
            int q3 = max(-128, min(127, (int)floorf(v3 * 64.0f)));
            uint32_t w = (uint32_t)(q0 & 255) | ((uint32_t)(q1 & 255) << 8)
                       | ((uint32_t)(q2 & 255) << 16) | ((uint32_t)(q3 & 255) << 24);
            *(uint32_t*)(Out + (((size_t)(bidx * NH + h1) * NN) + n) * HD + d1) = w;

            float v4 = acc[i][2][0] + b2a, v5 = acc[i][2][1] + b2b;
            int q4 = max(-128, min(127, (int)floorf(v4 * 64.0f)));
            int q5 = max(-128, min(127, (int)floorf(v5 * 64.0f)));
            *(uint16_t*)(Out + (((size_t)(bidx * NH + h2) * NN) + n) * HD + d2) =
                (uint16_t)((q4 & 255) | ((q5 & 255) << 8));
        }
    } else {
        if (t < 96) lcol[t] = 0;
        __syncthreads();
#pragma unroll
        for (int j = 0; j < 6; ++j) {
            const int lc = (j < 4) ? (tx * 4 + j) : (64 + tx * 2 + (j - 4));
            const int col = cl0 + lc;
            const int head = col >> 6, d = col & 63;
            const float bias = Bi[col];
            int s = 0;
            uint32_t w = 0;
#pragma unroll
            for (int i = 0; i < 4; ++i) {
                float v = ((j < 4) ? acc[i][j >> 1][j & 1] : acc[i][2][j - 4]) + bias;
                int qv = (int)floorf(v * 64.0f);
                qv = max(-128, min(127, qv));
                s += qv;
                w |= (uint32_t)(qv & 255) << (8 * i);
            }
            *(uint32_t*)(V8T + ((size_t)(bidx * NH + head) * HD + d) * NN
                         + n0 + ty * 4) = w;
            atomicAdd(&lcol[lc], s);
        }
        __syncthreads();
        if (t < 96) {
            const int col = cl0 + t;
            atomicAdd(&CS[(bidx * NH + (col >> 6)) * 64 + (col & 63)], lcol[t]);
        }
    }
}

// ---------------------------------------------------------------------------
// Kernel 2 v2 (unchanged from R18): MFMA attention, parallel B2/B4.
// ---------------------------------------------------------------------------
__global__ __launch_bounds__(256, 4) void attn_kernel(
    const int8_t* __restrict__ Q8, const int8_t* __restrict__ K8,
    const int8_t* __restrict__ V8T, const int* __restrict__ colsum,
    int8_t* __restrict__ CTX8)
{
    __shared__ int Lp[128 * 68];        // 34816 B packed logits (+pad words)
    __shared__ int gmaxw[128 * 4];      // 2048 B: group max -> prefix max (in place)
    __shared__ int esumw[128 * 8];      // 4096 B: reused as u16 esT[16 q][128 g]
    // total 40960 B -> 4 blocks/CU

    const int t = threadIdx.x;
    const int wid = t >> 6;
    const int lane = t & 63;
    const int quad = lane >> 4;
    const int l15 = lane & 15;
    const int bh = blockIdx.y;
    const int q0 = blockIdx.x * 16;
    const size_t base = (size_t)bh * NN * HD;
    const v4i zero = {0, 0, 0, 0};

    // ---- Phase A: logits via MFMA, K-frag prefetched TWO kt ahead ----
    v4i afrag = *(const v4i*)(Q8 + base + (size_t)(q0 + l15) * HD + quad * 16);
    {
        const int8_t* kp = K8 + base + (size_t)(wid * 32 * 16 + l15) * HD + quad * 16;
        v4i bf0 = *(const v4i*)kp;
        v4i bf1 = *(const v4i*)(kp + 16 * HD);
        for (int kt = wid * 32; kt < wid * 32 + 32; ++kt) {
            v4i curk = bf0;
            bf0 = bf1;
            kp += 16 * HD;
            bf1 = *(const v4i*)(kp + 16 * HD);   // kt+2 (overrun stays in d_ws)
            v4i d = __builtin_amdgcn_mfma_i32_16x16x64_i8(afrag, curk, zero, 0, 0, 0);
            int e[4];
#pragma unroll
            for (int r = 0; r < 4; ++r) {
                int lg = (d[r] * 5) >> 12;      // MA=5, SA=12: arith shr == floor
                e[r] = min(127, max(-128, lg));
            }
            int p01 = __builtin_amdgcn_perm(e[1], e[0], 0x00000400);
            int p23 = __builtin_amdgcn_perm(e[3], e[2], 0x00000400);
            Lp[kt * 68 + quad * 16 + l15] = __builtin_amdgcn_perm(p23, p01, 0x05040100);
        }
    }
    __syncthreads();

    // ---- Phase B1: per-(q,group) max; keep the logit words in registers ----
    int wb[2][16];                      // carried across B2 for reuse in B3
#pragma unroll
    for (int it = 0; it < 2; ++it) {
        const int task = t + it * 256;
        const int g = task & 127, qq = task >> 7;
        const int* p = &Lp[g * 68 + qq * 16];
#pragma unroll
        for (int a = 0; a < 4; ++a) {
            v4i v = *(const v4i*)&p[a * 4];
            wb[it][a * 4 + 0] = v.x; wb[it][a * 4 + 1] = v.y;
            wb[it][a * 4 + 2] = v.z; wb[it][a * 4 + 3] = v.w;
        }
        int mx[4];
#pragma unroll
        for (int b = 0; b < 4; ++b) {
            int m = INT_MIN;
#pragma unroll
            for (int j = 0; j < 16; ++j)
                m = max(m, (int)((unsigned)wb[it][j] << (8 * (3 - b))));
            mx[b] = m;
        }
        int p01 = __builtin_amdgcn_perm(mx[1], mx[0], 0x00000703);
        int p23 = __builtin_amdgcn_perm(mx[3], mx[2], 0x00000703);
        gmaxw[g * 4 + qq] = __builtin_amdgcn_perm(p23, p01, 0x05040100);
    }
    __syncthreads();

    // ---- Phase B2 (parallel): prefix max per q over 128 groups ----
    {
        const int q = t >> 4, c = t & 15;        // q row, chunk of 8 groups
        const int wq = q >> 2, bq = 8 * (q & 3);
        const int gbase = c * 8;
        int pm[8];
        int m = -128;
#pragma unroll
        for (int i = 0; i < 8; ++i) {
            int x = (int)(int8_t)(gmaxw[(gbase + i) * 4 + wq] >> bq);
            m = max(m, x);
            pm[i] = m;
        }
        int incl = m;                            // scan chunk totals over 16 lanes
#pragma unroll
        for (int dl = 1; dl < 16; dl <<= 1) {
            int v = __shfl_up(incl, dl, 16);
            if (c >= dl) incl = max(incl, v);
        }
        int excl = __shfl_up(incl, 1, 16);
        if (c == 0) excl = -128;
        int8_t* gb = (int8_t*)gmaxw;
#pragma unroll
        for (int i = 0; i < 8; ++i)
            gb[(gbase + i) * 16 + q] = (int8_t)max(excl, pm[i]);
    }
    __syncthreads();

    // ---- Phase B3: per-group exp sums vs prefix max; transposed store ----
    {
        uint16_t* esT = (uint16_t*)esumw;        // [16 q][128 g]
#pragma unroll
        for (int it = 0; it < 2; ++it) {
            const int task = t + it * 256;
            const int g = task & 127, qq = task >> 7;
            const int pw = gmaxw[g * 4 + qq];    // 4 prefix maxes (bytes)
#pragma unroll
            for (int b = 0; b < 4; ++b) {
                const int M = (int)(int8_t)(pw >> (8 * b));
                const int cb = 8 - M;
                int s = 0;
#pragma unroll
                for (int j = 0; j < 16; ++j) {
                    int x = (int)(int8_t)(wb[it][j] >> (8 * b));
                    int tt = x + cb;             // <= 8 (x <= prefix max)
                    s += (tt >= 0) ? (1 << tt) : 0;
                }
                esT[(qq * 4 + b) * 128 + g] = (uint16_t)s;
            }
        }
    }
    __syncthreads();

    // ---- Phase B4: sequential E recurrence, register-batched loads ----
    if (t < 16) {
        const int wq = t >> 2, bq = 8 * (t & 3);
        const uint16_t* esT = (const uint16_t*)esumw;
        int E = 0, Mp = -128;
#pragma unroll 4
        for (int g0 = 0; g0 < 128; g0 += 8) {
            int mw[8];
#pragma unroll
            for (int i = 0; i < 8; ++i) mw[i] = gmaxw[(g0 + i) * 4 + wq];
            int4 ev = *(const int4*)&esT[t * 128 + g0];
            unsigned ew[4] = {(unsigned)ev.x, (unsigned)ev.y,
                              (unsigned)ev.z, (unsigned)ev.w};
#pragma unroll
            for (int i = 0; i < 8; ++i) {
                int m = (int)(int8_t)(mw[i] >> bq);
                int d = m - Mp; if (d > 31) d = 31;
                int e = (int)((ew[i >> 1] >> (16 * (i & 1))) & 0xFFFF);
                E = (E >> d) + e;
                Mp = m;
            }
        }
        Lp[t * 68 + 64] = 65280 / E;             // inv <= 255 (E >= 256)
        Lp[t * 68 + 65] = Mp;                    // global max
    }
    __syncthreads();

    // ---- Phase C: ctx = (attn-128) . V via MFMA, V prefetched one kc ahead ----
    const int inv_l = Lp[l15 * 68 + 64];
    const int c24 = 24 - Lp[l15 * 68 + 65];
    const int sh8 = 8 * (l15 & 3);
    v4i accs[4] = {zero, zero, zero, zero};
    const int8_t* vtb = V8T + base;

    v4i bf[4];
    {
        const int koff0 = wid * 8 * 64 + quad * 16;
#pragma unroll
        for (int dtb = 0; dtb < 4; ++dtb)
            bf[dtb] = *(const v4i*)(vtb + (size_t)(dtb * 16 + l15) * NN + koff0);
    }
    for (int kc = wid * 8; kc < wid * 8 + 8; ++kc) {
        const int* lp = &Lp[(kc * 4 + quad) * 68 + (l15 >> 2) * 16];
        v4i w4[4];
#pragma unroll
        for (int r = 0; r < 4; ++r) w4[r] = *(const v4i*)&lp[4 * r];

        v4i b0 = bf[0], b1 = bf[1], b2 = bf[2], b3 = bf[3];
        const int koffn = (kc + 1) * 64 + quad * 16;     // overrun safe (in d_ws)
#pragma unroll
        for (int dtb = 0; dtb < 4; ++dtb)
            bf[dtb] = *(const v4i*)(vtb + (size_t)(dtb * 16 + l15) * NN + koffn);

        v4i a;
#pragma unroll
        for (int r = 0; r < 4; ++r) {
            int u[4];
#pragma unroll
            for (int c = 0; c < 4; ++c) {
                int x = (int)(int8_t)(w4[r][c] >> sh8);  // raw logit byte (q = l15)
                int t1 = x + c24;                        // 24 - (M - x), <= 24
                t1 = (t1 < 0) ? 0 : t1;
                u[c] = (int)((unsigned)inv_l << t1);     // attn in bits 24..31
            }
            int p01 = __builtin_amdgcn_perm(u[1], u[0], 0x00000703);
            int p23 = __builtin_amdgcn_perm(u[3], u[2], 0x00000703);
            a[r] = __builtin_amdgcn_perm(p23, p01, 0x05040100) ^ (int)0x80808080u;
        }
        accs[0] = __builtin_amdgcn_mfma_i32_16x16x64_i8(a, b0, accs[0], 0, 0, 0);
        accs[1] = __builtin_amdgcn_mfma_i32_16x16x64_i8(a, b1, accs[1], 0, 0, 0);
        accs[2] = __builtin_amdgcn_mfma_i32_16x16x64_i8(a, b2, accs[2], 0, 0, 0);
        accs[3] = __builtin_amdgcn_mfma_i32_16x16x64_i8(a, b3, accs[3], 0, 0, 0);
    }
    __syncthreads();                             // Lp dead -> reuse as reduction buf

    // ---- Cross-wave reduction + epilogue (reduction buffer = Lp) ----
    if (wid > 0) {
#pragma unroll
        for (int dt = 0; dt < 4; ++dt)
#pragma unroll
            for (int r = 0; r < 4; ++r)
                Lp[(dt * 4 + r) * 192 + (wid - 1) * 64 + lane] = accs[dt][r];
    }
    __syncthreads();
    if (wid == 0) {
        const int bb = bh / NH, hh = bh % NH;
        const int* cs = &colsum[bh * 64];
#pragma unroll
        for (int dt = 0; dt < 4; ++dt) {
            const int dcol = dt * 16 + l15;
            const int corr = cs[dcol] << 7;      // +128 * colsum
#pragma unroll
            for (int r = 0; r < 4; ++r) {
                const int i = dt * 4 + r;
                int val = accs[dt][r]
                        + Lp[i * 192 + 0 * 64 + lane]
                        + Lp[i * 192 + 1 * 64 + lane]
                        + Lp[i * 192 + 2 * 64 + lane];
                const int q = q0 + quad * 4 + r;
                val = (val + corr) >> 8;         // MAV=1, SAV=8 floor
                val = min(127, max(-128, val));
                CTX8[((size_t)(bb * NN + q)) * ND + hh * HD + dcol] = (int8_t)val;
            }
        }
    }
}

// ---------------------------------------------------------------------------
// Kernel 3a (unchanged): split Wo into f16 high/low planes once, k-blocked.
// ---------------------------------------------------------------------------
__global__ __launch_bounds__(384) void wo_convert_kernel(
    const float* __restrict__ Wo, half_t* __restrict__ WoHp, half_t* __restrict__ WoLp)
{
    const int col = blockIdx.x;
    const int k = threadIdx.x;
    float x = Wo[(size_t)col * ND + k];
    half_t h = (half_t)x;
    const size_t d = ((size_t)(k >> 3) * ND + col) * 8 + (k & 7);
    WoHp[d] = h;
    WoLp[d] = (half_t)((x - (float)h) * 2048.0f);
}

// ---------------------------------------------------------------------------
// Kernel 3b v4 (unchanged from R22): out GEMM, B prefetch + pitch 464.
// ---------------------------------------------------------------------------
__global__ __launch_bounds__(256) void out_gemm_kernel(
    const int8_t* __restrict__ CTX8, const half_t* __restrict__ WoHp,
    const half_t* __restrict__ WoLp, const float* __restrict__ Bo,
    float* __restrict__ out)
{
    __shared__ __attribute__((aligned(16))) int8_t Asl[64 * 464];

    const int t = threadIdx.x;
    const int wid = t >> 6;
    const int lane = t & 63;
    const int quad = lane >> 4;
    const int l15 = lane & 15;
    const int row0 = blockIdx.x * 64;
    const int c0 = blockIdx.y * 64;

#pragma unroll
    for (int pass = 0; pass < 6; ++pass) {
        const int cidx = pass * 256 + t;        // 0..1535
        const int row = cidx / 24;
        const int off = (cidx % 24) * 16;
        *(int4*)&Asl[row * 464 + off] =
            *(const int4*)(CTX8 + (size_t)(row0 + row) * ND + off);
    }

    const int8_t* alp = &Asl[(wid * 16 + l15) * 464 + quad * 8];
    const half_t* whp = WoHp + ((size_t)quad * ND + (c0 + l15)) * 8;
    const half_t* wlp = WoLp + ((size_t)quad * ND + (c0 + l15)) * 8;

    v4f accH[4], accL[4];
#pragma unroll
    for (int ct = 0; ct < 4; ct++) { accH[ct] = (v4f)0.0f; accL[ct] = (v4f)0.0f; }

    // prefetch k0=0's B fragments (global; overlaps the staging barrier)
    v8h bhv[4], blv[4];
#pragma unroll
    for (int ct = 0; ct < 4; ct++) {
        bhv[ct] = *(const v8h*)(whp + ct * 16 * 8);
        blv[ct] = *(const v8h*)(wlp + ct * 16 * 8);
    }
    __syncthreads();

    for (int k0 = 0; k0 < ND; k0 += 32) {
        int2 a8 = *(const int2*)(alp + k0);
        v8h af;
#pragma unroll
        for (int u = 0; u < 4; u++) {
            af[u]     = (half_t)(float)(int)(int8_t)((a8.x >> (8 * u)) & 0xFF);
            af[4 + u] = (half_t)(float)(int)(int8_t)((a8.y >> (8 * u)) & 0xFF);
        }
        v8h bh_c[4], bl_c[4];
#pragma unroll
        for (int ct = 0; ct < 4; ct++) { bh_c[ct] = bhv[ct]; bl_c[ct] = blv[ct]; }

        // prefetch next iteration's B (guard avoids OOB on the last iter)
        const size_t kbn = (size_t)(((k0 + 32 < ND) ? (k0 + 32) : 0) >> 3) * ND * 8;
#pragma unroll
        for (int ct = 0; ct < 4; ct++) {
            bhv[ct] = *(const v8h*)(whp + kbn + ct * 16 * 8);
            blv[ct] = *(const v8h*)(wlp + kbn + ct * 16 * 8);
        }

#pragma unroll
        for (int ct = 0; ct < 4; ct++) {
            accH[ct] = __builtin_amdgcn_mfma_f32_16x16x32_f16(af, bh_c[ct], accH[ct], 0, 0, 0);
            accL[ct] = __builtin_amdgcn_mfma_f32_16x16x32_f16(af, bl_c[ct], accL[ct], 0, 0, 0);
        }
    }

    const float inv2048 = 4.8828125e-4f;
#pragma unroll
    for (int ct = 0; ct < 4; ct++) {
        const int c = c0 + ct * 16 + l15;
        const float bias = Bo[c];
#pragma unroll
        for (int r = 0; r < 4; r++) {
            const int row = row0 + wid * 16 + quad * 4 + r;
            float v = accH[ct][r] + accL[ct][r] * inv2048 + bias;
            float rq = floorf(v * 2.0f);
            rq = fminf(fmaxf(rq, -128.0f), 127.0f);
            out[(size_t)row * ND + c] = rq;
        }
    }
}

extern "C" void kernel_launch(void* const* d_in, const int* in_sizes, int n_in,
                              void* d_out, int out_size, void* d_ws, size_t ws_size,
                              hipStream_t stream)
{
    const float* x  = (const float*)d_in[0];
    const float* wq = (const float*)d_in[1];
    const float* bq = (const float*)d_in[2];
    const float* wk = (const float*)d_in[3];
    const float* bk = (const float*)d_in[4];
    const float* wv = (const float*)d_in[5];
    const float* bv = (const float*)d_in[6];
    const float* wo = (const float*)d_in[7];
    const float* bo = (const float*)d_in[8];
    float* out = (float*)d_out;

    const size_t MAT = (size_t)ROWS * ND;
    int8_t* Q8  = (int8_t*)d_ws;
    int8_t* K8  = Q8 + MAT;
    int8_t* V8T = K8 + MAT;
    int8_t* C8  = V8T + MAT;
    int*    CS  = (int*)(C8 + MAT);
    half_t* WoHp = (half_t*)(CS + NB * NH * 64);
    half_t* WoLp = WoHp + (size_t)ND * ND;

    hipMemsetAsync(CS, 0, (size_t)NB * NH * 64 * sizeof(int), stream);
    wo_convert_kernel<<<dim3(ND), 384, 0, stream>>>(wo, WoHp, WoLp);
    qkv_gemm_kernel<<<dim3(ROWS / 64, 12), 256, 0, stream>>>(
        x, wq, wk, wv, bq, bk, bv, Q8, K8, V8T, CS);
    attn_kernel<<<dim3(NN / 16, NB * NH), 256, 0, stream>>>(Q8, K8, V8T, CS, C8);
    out_gemm_kernel<<<dim3(ROWS / 64, ND / 64), 256, 0, stream>>>(C8, WoHp, WoLp, bo, out);
}

// Round 15
// 254.360 us; speedup vs baseline: 1.0985x; 1.0985x over previous
//
#include <hip/hip_runtime.h>
#include <stdint.h>

// Problem constants (B=4, N=2048, D=384, heads=6, hd=64)
#define NB 4
#define NN 2048
#define ND 384
#define NH 6
#define HD 64
#define ROWS (NB * NN)  // 8192

typedef int v4i __attribute__((ext_vector_type(4)));
typedef float v4f __attribute__((ext_vector_type(4)));
typedef float v2f __attribute__((ext_vector_type(2)));
typedef _Float16 half_t;
typedef half_t v8h __attribute__((ext_vector_type(8)));

// VOP3P packed fp32 FMA with op_sel scalar-broadcast (no dup movs).
#define PK_FMA_LO(accv, ap, bp)                                            \
    asm("v_pk_fma_f32 %0, %1, %2, %0 op_sel:[0,0,0] op_sel_hi:[0,1,1]"     \
        : "+v"(accv) : "v"(ap), "v"(bp))
#define PK_FMA_HI(accv, ap, bp)                                            \
    asm("v_pk_fma_f32 %0, %1, %2, %0 op_sel:[1,0,0] op_sel_hi:[1,1,1]"     \
        : "+v"(accv) : "v"(ap), "v"(bp))

// ---------------------------------------------------------------------------
// Kernel 1 v12 (R24 resubmit; R25): fused QKV projection — best-measured R19
// config (94 us). ONLY change vs R19: V written in k-chunked layout
// Vt[bh][n>>4][d][16B] so attn's Phase C V-loads coalesce.
// Same GEMM core -> bit-identical Q/K/V values.
// ---------------------------------------------------------------------------
__global__ __launch_bounds__(256, 3) void qkv_gemm_kernel(
    const float* __restrict__ X,
    const float* __restrict__ Wq, const float* __restrict__ Wk, const float* __restrict__ Wv,
    const float* __restrict__ Bq, const float* __restrict__ Bk, const float* __restrict__ Bv,
    int8_t* __restrict__ Q8, int8_t* __restrict__ K8, int8_t* __restrict__ V8T,
    int* __restrict__ CS)
{
    __shared__ __attribute__((aligned(16))) float As[2][16][132];  // [buf][k][row]
    __shared__ __attribute__((aligned(16))) float Bs[2][16][100];  // [buf][k][col]
    __shared__ int lcol[96];

    const int t = threadIdx.x;          // 0..255
    const int tx = t & 15;              // col group (6 cols: 4 + 2)
    const int ty = t >> 4;              // row group (8 rows)
    const int row0 = blockIdx.x * 128;
    const int m = blockIdx.y >> 2;      // 0=Q 1=K 2=V
    const int cl0 = (blockIdx.y & 3) * 96;
    const float* W = (m == 0) ? Wq : (m == 1) ? Wk : Wv;
    const float* Bi = (m == 0) ? Bq : (m == 1) ? Bk : Bv;

    const int sr = t >> 1;              // 0..127
    const int sk = (t & 1) * 8;         // k sub-chunk 0 or 8
    const float* xp = X + (size_t)(row0 + sr) * ND + sk;
    const float* wp = W + (size_t)(cl0 + sr) * ND + sk;    // sr<96 when t<192

    v2f acc[8][3];
#pragma unroll
    for (int i = 0; i < 8; ++i)
#pragma unroll
        for (int p = 0; p < 3; ++p) acc[i][p] = (v2f)0.0f;

    float4 xa0 = *(const float4*)xp;
    float4 xa1 = *(const float4*)(xp + 4);
    float4 wb0, wb1;
    if (t < 192) { wb0 = *(const float4*)wp; wb1 = *(const float4*)(wp + 4); }

    int cur = 0;
    for (int k0 = 0; k0 < ND; k0 += 16) {
        As[cur][sk + 0][sr] = xa0.x; As[cur][sk + 1][sr] = xa0.y;
        As[cur][sk + 2][sr] = xa0.z; As[cur][sk + 3][sr] = xa0.w;
        As[cur][sk + 4][sr] = xa1.x; As[cur][sk + 5][sr] = xa1.y;
        As[cur][sk + 6][sr] = xa1.z; As[cur][sk + 7][sr] = xa1.w;
        if (t < 192) {
            Bs[cur][sk + 0][sr] = wb0.x; Bs[cur][sk + 1][sr] = wb0.y;
            Bs[cur][sk + 2][sr] = wb0.z; Bs[cur][sk + 3][sr] = wb0.w;
            Bs[cur][sk + 4][sr] = wb1.x; Bs[cur][sk + 5][sr] = wb1.y;
            Bs[cur][sk + 6][sr] = wb1.z; Bs[cur][sk + 7][sr] = wb1.w;
        }

        if (k0 + 16 < ND) {
            xa0 = *(const float4*)(xp + k0 + 16);
            xa1 = *(const float4*)(xp + k0 + 20);
            if (t < 192) {
                wb0 = *(const float4*)(wp + k0 + 16);
                wb1 = *(const float4*)(wp + k0 + 20);
            }
        }
        __syncthreads();

#pragma unroll
        for (int kk = 0; kk < 16; ++kk) {
            v4f a0 = *(const v4f*)&As[cur][kk][ty * 8];       // b128
            v4f a1 = *(const v4f*)&As[cur][kk][ty * 8 + 4];   // b128
            v4f b0 = *(const v4f*)&Bs[cur][kk][tx * 4];       // b128
            v2f bp2 = *(const v2f*)&Bs[cur][kk][64 + tx * 2]; // b64
            v2f ap0 = __builtin_shufflevector(a0, a0, 0, 1);
            v2f ap1 = __builtin_shufflevector(a0, a0, 2, 3);
            v2f ap2 = __builtin_shufflevector(a1, a1, 0, 1);
            v2f ap3 = __builtin_shufflevector(a1, a1, 2, 3);
            v2f bp0 = __builtin_shufflevector(b0, b0, 0, 1);
            v2f bp1 = __builtin_shufflevector(b0, b0, 2, 3);

            PK_FMA_LO(acc[0][0], ap0, bp0); PK_FMA_LO(acc[0][1], ap0, bp1);
            PK_FMA_LO(acc[0][2], ap0, bp2);
            PK_FMA_HI(acc[1][0], ap0, bp0); PK_FMA_HI(acc[1][1], ap0, bp1);
            PK_FMA_HI(acc[1][2], ap0, bp2);

            PK_FMA_LO(acc[2][0], ap1, bp0); PK_FMA_LO(acc[2][1], ap1, bp1);
            PK_FMA_LO(acc[2][2], ap1, bp2);
            PK_FMA_HI(acc[3][0], ap1, bp0); PK_FMA_HI(acc[3][1], ap1, bp1);
            PK_FMA_HI(acc[3][2], ap1, bp2);

            PK_FMA_LO(acc[4][0], ap2, bp0); PK_FMA_LO(acc[4][1], ap2, bp1);
            PK_FMA_LO(acc[4][2], ap2, bp2);
            PK_FMA_HI(acc[5][0], ap2, bp0); PK_FMA_HI(acc[5][1], ap2, bp1);
            PK_FMA_HI(acc[5][2], ap2, bp2);

            PK_FMA_LO(acc[6][0], ap3, bp0); PK_FMA_LO(acc[6][1], ap3, bp1);
            PK_FMA_LO(acc[6][2], ap3, bp2);
            PK_FMA_HI(acc[7][0], ap3, bp0); PK_FMA_HI(acc[7][1], ap3, bp1);
            PK_FMA_HI(acc[7][2], ap3, bp2);
        }
        cur ^= 1;
    }

    const int bidx = row0 >> 11;
    const int n0 = row0 & 2047;
    const int c1 = cl0 + tx * 4;
    const int c2 = cl0 + 64 + tx * 2;
    const int h1 = c1 >> 6, d1 = c1 & 63;
    const int h2 = c2 >> 6, d2 = c2 & 63;

    if (m != 2) {
        int8_t* Out = (m == 0) ? Q8 : K8;
        const float b1a = Bi[c1], b1b = Bi[c1 + 1], b1c = Bi[c1 + 2], b1d = Bi[c1 + 3];
        const float b2a = Bi[c2], b2b = Bi[c2 + 1];
#pragma unroll
        for (int i = 0; i < 8; ++i) {
            const int n = n0 + ty * 8 + i;
            float v0 = acc[i][0][0] + b1a, v1 = acc[i][0][1] + b1b;
            float v2 = acc[i][1][0] + b1c, v3 = acc[i][1][1] + b1d;
            int q0 = max(-128, min(127, (int)floorf(v0 * 64.0f)));
            int q1 = max(-128, min(127, (int)floorf(v1 * 64.0f)));
            int q2 = max(-128, min(127, (int)floorf(v2 * 64.0f)));
            int q3 = max(-128, min(127, (int)floorf(v3 * 64.0f)));
            uint32_t w = (uint32_t)(q0 & 255) | ((uint32_t)(q1 & 255) << 8)
                       | ((uint32_t)(q2 & 255) << 16) | ((uint32_t)(q3 & 255) << 24);
            *(uint32_t*)(Out + (((size_t)(bidx * NH + h1) * NN) + n) * HD + d1) = w;

            float v4 = acc[i][2][0] + b2a, v5 = acc[i][2][1] + b2b;
            int q4 = max(-128, min(127, (int)floorf(v4 * 64.0f)));
            int q5 = max(-128, min(127, (int)floorf(v5 * 64.0f)));
            *(uint16_t*)(Out + (((size_t)(bidx * NH + h2) * NN) + n) * HD + d2) =
                (uint16_t)((q4 & 255) | ((q5 & 255) << 8));
        }
    } else {
        if (t < 96) lcol[t] = 0;
        __syncthreads();
        // k-chunked V layout: Vt[bh][chunk=n>>4][d][16B].
        // This thread's 8 rows n0+ty*8..+7 live in chunk n0>>4 + (ty>>1),
        // byte offset (ty&1)*8 .. +7 (w[0] then w[1]).
#pragma unroll
        for (int j = 0; j < 6; ++j) {
            const int lc = (j < 4) ? (tx * 4 + j) : (64 + tx * 2 + (j - 4));
            const int col = cl0 + lc;
            const int head = col >> 6, d = col & 63;
            const float bias = Bi[col];
            int s = 0;
            uint32_t w[2] = {0u, 0u};
#pragma unroll
            for (int i = 0; i < 8; ++i) {
                float v = ((j < 4) ? acc[i][j >> 1][j & 1] : acc[i][2][j - 4]) + bias;
                int qv = (int)floorf(v * 64.0f);
                qv = max(-128, min(127, qv));
                s += qv;
                w[i >> 2] |= (uint32_t)(qv & 255) << (8 * (i & 3));
            }
            uint32_t* dst = (uint32_t*)(V8T
                + ((((size_t)(bidx * NH + head)) * 128 + (n0 >> 4) + (ty >> 1)) * 64 + d) * 16
                + (ty & 1) * 8);
            dst[0] = w[0];
            dst[1] = w[1];
            atomicAdd(&lcol[lc], s);
        }
        __syncthreads();
        if (t < 96) {
            const int col = cl0 + t;
            atomicAdd(&CS[(bidx * NH + (col >> 6)) * 64 + (col & 63)], lcol[t]);
        }
    }
}

// ---------------------------------------------------------------------------
// Kernel 2 v3 (R24 resubmit): MFMA attention (R18 base). ONLY change:
// Phase C reads V from the k-chunked layout Vt[bh][k>>4][d][16B] -> each
// v4i load is 64 consecutive-d lanes x 16B = fully coalesced 1KB (was
// lane-stride-2048, 64 lines/inst, ~4x L2 amplification).
// Same values -> bit-identical.
// ---------------------------------------------------------------------------
__global__ __launch_bounds__(256, 4) void attn_kernel(
    const int8_t* __restrict__ Q8, const int8_t* __restrict__ K8,
    const int8_t* __restrict__ V8T, const int* __restrict__ colsum,
    int8_t* __restrict__ CTX8)
{
    __shared__ int Lp[128 * 68];        // 34816 B packed logits (+pad words)
    __shared__ int gmaxw[128 * 4];      // 2048 B: group max -> prefix max (in place)
    __shared__ int esumw[128 * 8];      // 4096 B: reused as u16 esT[16 q][128 g]
    // total 40960 B -> 4 blocks/CU

    const int t = threadIdx.x;
    const int wid = t >> 6;
    const int lane = t & 63;
    const int quad = lane >> 4;
    const int l15 = lane & 15;
    const int bh = blockIdx.y;
    const int q0 = blockIdx.x * 16;
    const size_t base = (size_t)bh * NN * HD;
    const v4i zero = {0, 0, 0, 0};

    // ---- Phase A: logits via MFMA, K-frag prefetched TWO kt ahead ----
    v4i afrag = *(const v4i*)(Q8 + base + (size_t)(q0 + l15) * HD + quad * 16);
    {
        const int8_t* kp = K8 + base + (size_t)(wid * 32 * 16 + l15) * HD + quad * 16;
        v4i bf0 = *(const v4i*)kp;
        v4i bf1 = *(const v4i*)(kp + 16 * HD);
        for (int kt = wid * 32; kt < wid * 32 + 32; ++kt) {
            v4i curk = bf0;
            bf0 = bf1;
            kp += 16 * HD;
            bf1 = *(const v4i*)(kp + 16 * HD);   // kt+2 (overrun stays in d_ws)
            v4i d = __builtin_amdgcn_mfma_i32_16x16x64_i8(afrag, curk, zero, 0, 0, 0);
            int e[4];
#pragma unroll
            for (int r = 0; r < 4; ++r) {
                int lg = (d[r] * 5) >> 12;      // MA=5, SA=12: arith shr == floor
                e[r] = min(127, max(-128, lg));
            }
            int p01 = __builtin_amdgcn_perm(e[1], e[0], 0x00000400);
            int p23 = __builtin_amdgcn_perm(e[3], e[2], 0x00000400);
            Lp[kt * 68 + quad * 16 + l15] = __builtin_amdgcn_perm(p23, p01, 0x05040100);
        }
    }
    __syncthreads();

    // ---- Phase B1: per-(q,group) max; keep the logit words in registers ----
    int wb[2][16];                      // carried across B2 for reuse in B3
#pragma unroll
    for (int it = 0; it < 2; ++it) {
        const int task = t + it * 256;
        const int g = task & 127, qq = task >> 7;
        const int* p = &Lp[g * 68 + qq * 16];
#pragma unroll
        for (int a = 0; a < 4; ++a) {
            v4i v = *(const v4i*)&p[a * 4];
            wb[it][a * 4 + 0] = v.x; wb[it][a * 4 + 1] = v.y;
            wb[it][a * 4 + 2] = v.z; wb[it][a * 4 + 3] = v.w;
        }
        int mx[4];
#pragma unroll
        for (int b = 0; b < 4; ++b) {
            int m = INT_MIN;
#pragma unroll
            for (int j = 0; j < 16; ++j)
                m = max(m, (int)((unsigned)wb[it][j] << (8 * (3 - b))));
            mx[b] = m;
        }
        int p01 = __builtin_amdgcn_perm(mx[1], mx[0], 0x00000703);
        int p23 = __builtin_amdgcn_perm(mx[3], mx[2], 0x00000703);
        gmaxw[g * 4 + qq] = __builtin_amdgcn_perm(p23, p01, 0x05040100);
    }
    __syncthreads();

    // ---- Phase B2 (parallel): prefix max per q over 128 groups ----
    {
        const int q = t >> 4, c = t & 15;        // q row, chunk of 8 groups
        const int wq = q >> 2, bq = 8 * (q & 3);
        const int gbase = c * 8;
        int pm[8];
        int m = -128;
#pragma unroll
        for (int i = 0; i < 8; ++i) {
            int x = (int)(int8_t)(gmaxw[(gbase + i) * 4 + wq] >> bq);
            m = max(m, x);
            pm[i] = m;
        }
        int incl = m;                            // scan chunk totals over 16 lanes
#pragma unroll
        for (int dl = 1; dl < 16; dl <<= 1) {
            int v = __shfl_up(incl, dl, 16);
            if (c >= dl) incl = max(incl, v);
        }
        int excl = __shfl_up(incl, 1, 16);
        if (c == 0) excl = -128;
        int8_t* gb = (int8_t*)gmaxw;
#pragma unroll
        for (int i = 0; i < 8; ++i)
            gb[(gbase + i) * 16 + q] = (int8_t)max(excl, pm[i]);
    }
    __syncthreads();

    // ---- Phase B3: per-group exp sums vs prefix max; transposed store ----
    {
        uint16_t* esT = (uint16_t*)esumw;        // [16 q][128 g]
#pragma unroll
        for (int it = 0; it < 2; ++it) {
            const int task = t + it * 256;
            const int g = task & 127, qq = task >> 7;
            const int pw = gmaxw[g * 4 + qq];    // 4 prefix maxes (bytes)
#pragma unroll
            for (int b = 0; b < 4; ++b) {
                const int M = (int)(int8_t)(pw >> (8 * b));
                const int cb = 8 - M;
                int s = 0;
#pragma unroll
                for (int j = 0; j < 16; ++j) {
                    int x = (int)(int8_t)(wb[it][j] >> (8 * b));
                    int tt = x + cb;             // <= 8 (x <= prefix max)
                    s += (tt >= 0) ? (1 << tt) : 0;
                }
                esT[(qq * 4 + b) * 128 + g] = (uint16_t)s;
            }
        }
    }
    __syncthreads();

    // ---- Phase B4: sequential E recurrence, register-batched loads ----
    if (t < 16) {
        const int wq = t >> 2, bq = 8 * (t & 3);
        const uint16_t* esT = (const uint16_t*)esumw;
        int E = 0, Mp = -128;
#pragma unroll 4
        for (int g0 = 0; g0 < 128; g0 += 8) {
            int mw[8];
#pragma unroll
            for (int i = 0; i < 8; ++i) mw[i] = gmaxw[(g0 + i) * 4 + wq];
            int4 ev = *(const int4*)&esT[t * 128 + g0];
            unsigned ew[4] = {(unsigned)ev.x, (unsigned)ev.y,
                              (unsigned)ev.z, (unsigned)ev.w};
#pragma unroll
            for (int i = 0; i < 8; ++i) {
                int m = (int)(int8_t)(mw[i] >> bq);
                int d = m - Mp; if (d > 31) d = 31;
                int e = (int)((ew[i >> 1] >> (16 * (i & 1))) & 0xFFFF);
                E = (E >> d) + e;
                Mp = m;
            }
        }
        Lp[t * 68 + 64] = 65280 / E;             // inv <= 255 (E >= 256)
        Lp[t * 68 + 65] = Mp;                    // global max
    }
    __syncthreads();

    // ---- Phase C: ctx = (attn-128) . V via MFMA, V prefetched one kc ahead ----
    const int inv_l = Lp[l15 * 68 + 64];
    const int c24 = 24 - Lp[l15 * 68 + 65];
    const int sh8 = 8 * (l15 & 3);
    v4i accs[4] = {zero, zero, zero, zero};
    const int8_t* vtb = V8T + base;              // = bh * 128 chunks * 64 d * 16B

    v4i bf[4];
    {
        const int ch0 = wid * 32 + quad;         // chunk = kc*4+quad at kc=wid*8
#pragma unroll
        for (int dtb = 0; dtb < 4; ++dtb)
            bf[dtb] = *(const v4i*)(vtb + ((size_t)ch0 * 64 + dtb * 16 + l15) * 16);
    }
    for (int kc = wid * 8; kc < wid * 8 + 8; ++kc) {
        const int* lp = &Lp[(kc * 4 + quad) * 68 + (l15 >> 2) * 16];
        v4i w4[4];
#pragma unroll
        for (int r = 0; r < 4; ++r) w4[r] = *(const v4i*)&lp[4 * r];

        v4i b0 = bf[0], b1 = bf[1], b2 = bf[2], b3 = bf[3];
        const int chn = (kc + 1) * 4 + quad;     // next chunk (overrun -> C8, safe)
#pragma unroll
        for (int dtb = 0; dtb < 4; ++dtb)
            bf[dtb] = *(const v4i*)(vtb + ((size_t)chn * 64 + dtb * 16 + l15) * 16);

        v4i a;
#pragma unroll
        for (int r = 0; r < 4; ++r) {
            int u[4];
#pragma unroll
            for (int c = 0; c < 4; ++c) {
                int x = (int)(int8_t)(w4[r][c] >> sh8);  // raw logit byte (q = l15)
                int t1 = x + c24;                        // 24 - (M - x), <= 24
                t1 = (t1 < 0) ? 0 : t1;
                u[c] = (int)((unsigned)inv_l << t1);     // attn in bits 24..31
            }
            int p01 = __builtin_amdgcn_perm(u[1], u[0], 0x00000703);
            int p23 = __builtin_amdgcn_perm(u[3], u[2], 0x00000703);
            a[r] = __builtin_amdgcn_perm(p23, p01, 0x05040100) ^ (int)0x80808080u;
        }
        accs[0] = __builtin_amdgcn_mfma_i32_16x16x64_i8(a, b0, accs[0], 0, 0, 0);
        accs[1] = __builtin_amdgcn_mfma_i32_16x16x64_i8(a, b1, accs[1], 0, 0, 0);
        accs[2] = __builtin_amdgcn_mfma_i32_16x16x64_i8(a, b2, accs[2], 0, 0, 0);
        accs[3] = __builtin_amdgcn_mfma_i32_16x16x64_i8(a, b3, accs[3], 0, 0, 0);
    }
    __syncthreads();                             // Lp dead -> reuse as reduction buf

    // ---- Cross-wave reduction + epilogue (reduction buffer = Lp) ----
    if (wid > 0) {
#pragma unroll
        for (int dt = 0; dt < 4; ++dt)
#pragma unroll
            for (int r = 0; r < 4; ++r)
                Lp[(dt * 4 + r) * 192 + (wid - 1) * 64 + lane] = accs[dt][r];
    }
    __syncthreads();
    if (wid == 0) {
        const int bb = bh / NH, hh = bh % NH;
        const int* cs = &colsum[bh * 64];
#pragma unroll
        for (int dt = 0; dt < 4; ++dt) {
            const int dcol = dt * 16 + l15;
            const int corr = cs[dcol] << 7;      // +128 * colsum
#pragma unroll
            for (int r = 0; r < 4; ++r) {
                const int i = dt * 4 + r;
                int val = accs[dt][r]
                        + Lp[i * 192 + 0 * 64 + lane]
                        + Lp[i * 192 + 1 * 64 + lane]
                        + Lp[i * 192 + 2 * 64 + lane];
                const int q = q0 + quad * 4 + r;
                val = (val + corr) >> 8;         // MAV=1, SAV=8 floor
                val = min(127, max(-128, val));
                CTX8[((size_t)(bb * NN + q)) * ND + hh * HD + dcol] = (int8_t)val;
            }
        }
    }
}

// ---------------------------------------------------------------------------
// Kernel 3a (unchanged): split Wo into f16 high/low planes once, k-blocked.
// ---------------------------------------------------------------------------
__global__ __launch_bounds__(384) void wo_convert_kernel(
    const float* __restrict__ Wo, half_t* __restrict__ WoHp, half_t* __restrict__ WoLp)
{
    const int col = blockIdx.x;
    const int k = threadIdx.x;
    float x = Wo[(size_t)col * ND + k];
    half_t h = (half_t)x;
    const size_t d = ((size_t)(k >> 3) * ND + col) * 8 + (k & 7);
    WoHp[d] = h;
    WoLp[d] = (half_t)((x - (float)h) * 2048.0f);
}

// ---------------------------------------------------------------------------
// Kernel 3b v4 (unchanged from R22): out GEMM, B prefetch + pitch 464.
// ---------------------------------------------------------------------------
__global__ __launch_bounds__(256) void out_gemm_kernel(
    const int8_t* __restrict__ CTX8, const half_t* __restrict__ WoHp,
    const half_t* __restrict__ WoLp, const float* __restrict__ Bo,
    float* __restrict__ out)
{
    __shared__ __attribute__((aligned(16))) int8_t Asl[64 * 464];

    const int t = threadIdx.x;
    const int wid = t >> 6;
    const int lane = t & 63;
    const int quad = lane >> 4;
    const int l15 = lane & 15;
    const int row0 = blockIdx.x * 64;
    const int c0 = blockIdx.y * 64;

#pragma unroll
    for (int pass = 0; pass < 6; ++pass) {
        const int cidx = pass * 256 + t;        // 0..1535
        const int row = cidx / 24;
        const int off = (cidx % 24) * 16;
        *(int4*)&Asl[row * 464 + off] =
            *(const int4*)(CTX8 + (size_t)(row0 + row) * ND + off);
    }

    const int8_t* alp = &Asl[(wid * 16 + l15) * 464 + quad * 8];
    const half_t* whp = WoHp + ((size_t)quad * ND + (c0 + l15)) * 8;
    const half_t* wlp = WoLp + ((size_t)quad * ND + (c0 + l15)) * 8;

    v4f accH[4], accL[4];
#pragma unroll
    for (int ct = 0; ct < 4; ct++) { accH[ct] = (v4f)0.0f; accL[ct] = (v4f)0.0f; }

    // prefetch k0=0's B fragments (global; overlaps the staging barrier)
    v8h bhv[4], blv[4];
#pragma unroll
    for (int ct = 0; ct < 4; ct++) {
        bhv[ct] = *(const v8h*)(whp + ct * 16 * 8);
        blv[ct] = *(const v8h*)(wlp + ct * 16 * 8);
    }
    __syncthreads();

    for (int k0 = 0; k0 < ND; k0 += 32) {
        int2 a8 = *(const int2*)(alp + k0);
        v8h af;
#pragma unroll
        for (int u = 0; u < 4; u++) {
            af[u]     = (half_t)(float)(int)(int8_t)((a8.x >> (8 * u)) & 0xFF);
            af[4 + u] = (half_t)(float)(int)(int8_t)((a8.y >> (8 * u)) & 0xFF);
        }
        v8h bh_c[4], bl_c[4];
#pragma unroll
        for (int ct = 0; ct < 4; ct++) { bh_c[ct] = bhv[ct]; bl_c[ct] = blv[ct]; }

        // prefetch next iteration's B (guard avoids OOB on the last iter)
        const size_t kbn = (size_t)(((k0 + 32 < ND) ? (k0 + 32) : 0) >> 3) * ND * 8;
#pragma unroll
        for (int ct = 0; ct < 4; ct++) {
            bhv[ct] = *(const v8h*)(whp + kbn + ct * 16 * 8);
            blv[ct] = *(const v8h*)(wlp + kbn + ct * 16 * 8);
        }

#pragma unroll
        for (int ct = 0; ct < 4; ct++) {
            accH[ct] = __builtin_amdgcn_mfma_f32_16x16x32_f16(af, bh_c[ct], accH[ct], 0, 0, 0);
            accL[ct] = __builtin_amdgcn_mfma_f32_16x16x32_f16(af, bl_c[ct], accL[ct], 0, 0, 0);
        }
    }

    const float inv2048 = 4.8828125e-4f;
#pragma unroll
    for (int ct = 0; ct < 4; ct++) {
        const int c = c0 + ct * 16 + l15;
        const float bias = Bo[c];
#pragma unroll
        for (int r = 0; r < 4; r++) {
            const int row = row0 + wid * 16 + quad * 4 + r;
            float v = accH[ct][r] + accL[ct][r] * inv2048 + bias;
            float rq = floorf(v * 2.0f);
            rq = fminf(fmaxf(rq, -128.0f), 127.0f);
            out[(size_t)row * ND + c] = rq;
        }
    }
}

extern "C" void kernel_launch(void* const* d_in, const int* in_sizes, int n_in,
                              void* d_out, int out_size, void* d_ws, size_t ws_size,
                              hipStream_t stream)
{
    const float* x  = (const float*)d_in[0];
    const float* wq = (const float*)d_in[1];
    const float* bq = (const float*)d_in[2];
    const float* wk = (const float*)d_in[3];
    const float* bk = (const float*)d_in[4];
    const float* wv = (const float*)d_in[5];
    const float* bv = (const float*)d_in[6];
    const float* wo = (const float*)d_in[7];
    const float* bo = (const float*)d_in[8];
    float* out = (float*)d_out;

    const size_t MAT = (size_t)ROWS * ND;
    int8_t* Q8  = (int8_t*)d_ws;
    int8_t* K8  = Q8 + MAT;
    int8_t* V8T = K8 + MAT;      // k-chunked Vt layout, same size
    int8_t* C8  = V8T + MAT;
    int*    CS  = (int*)(C8 + MAT);
    half_t* WoHp = (half_t*)(CS + NB * NH * 64);
    half_t* WoLp = WoHp + (size_t)ND * ND;

    hipMemsetAsync(CS, 0, (size_t)NB * NH * 64 * sizeof(int), stream);
    wo_convert_kernel<<<dim3(ND), 384, 0, stream>>>(wo, WoHp, WoLp);
    qkv_gemm_kernel<<<dim3(ROWS / 128, 12), 256, 0, stream>>>(
        x, wq, wk, wv, bq, bk, bv, Q8, K8, V8T, CS);
    attn_kernel<<<dim3(NN / 16, NB * NH), 256, 0, stream>>>(Q8, K8, V8T, CS, C8);
    out_gemm_kernel<<<dim3(ROWS / 64, ND / 64), 256, 0, stream>>>(C8, WoHp, WoLp, bo, out);
}